// Round 1
// baseline (102.008 us; speedup 1.0000x reference)
//
#include <hip/hip_runtime.h>
#include <math.h>

// Problem constants (from reference): N=256, D=128, C=1000, Q=262144
constexpr int  Nn = 256;
constexpr int  Dd = 128;
constexpr int  Cc = 1000;
constexpr int  Qq = 262144;
constexpr float PROTO_M = 0.99f;

// ---- float4-unit segment sizes for the big fused copy kernel ----
constexpr long SEG_OUTX  = (long)Nn * Cc / 4;        // 64000   output_x copy
constexpr long SEG_QX    = (long)Nn * Dd / 4;        // 8192    q_x -> features
constexpr long SEG_QUEUE = (long)Qq * Dd / 4;        // 8388608 queue -> features + new_queue
constexpr long SEG_TGT   = (long)(2 * Nn + Qq) / 4;  // 65664   targets
constexpr long SEG_QY    = (long)Qq / 4;             // 65536   new_queue_Y / new_isID

// ---- output offsets in float units (tuple members flattened in order) ----
constexpr long OFF_OUTX = 0;
constexpr long OFF_FEAT = (long)Nn * Cc;                      // 256000
constexpr long OFF_TGT  = OFF_FEAT + (long)(2 * Nn + Qq) * Dd; // 33875968
constexpr long OFF_PROT = OFF_TGT + (2 * Nn + Qq);             // 34138624
constexpr long OFF_NQ   = OFF_PROT + (long)Cc * Dd;            // 34266624
constexpr long OFF_NQY  = OFF_NQ + (long)Qq * Dd;              // 67821056
constexpr long OFF_ISID = OFF_NQY + Qq;                        // 68083200
constexpr long OFF_PTR  = OFF_ISID + Qq;                       // 68345344

__global__ __launch_bounds__(256) void fuse_kernel(
    const float4* __restrict__ q_x4, const float4* __restrict__ k_x4,
    const float4* __restrict__ output_x4, const float4* __restrict__ queue4,
    const float4* __restrict__ isID4, const int* __restrict__ Y,
    const int* __restrict__ queue_Y, const int* __restrict__ ptr_p,
    float* __restrict__ out)
{
    const long total = SEG_OUTX + 2 * SEG_QX + SEG_QUEUE + SEG_TGT + 2 * SEG_QY + 1;
    float4* out4 = (float4*)out;
    const int4* Y4  = (const int4*)Y;
    const int4* qY4 = (const int4*)queue_Y;

    const int ptr_raw = *ptr_p;
    // jax dynamic_update_slice clamps the start index so the slice fits
    const int ptr = min(max(ptr_raw, 0), Qq - Nn);

    const long stride = (long)gridDim.x * blockDim.x;
    for (long v = (long)blockIdx.x * blockDim.x + threadIdx.x; v < total; v += stride) {
        long r = v;
        // --- output_x passthrough ---
        if (r < SEG_OUTX) { out4[OFF_OUTX / 4 + r] = output_x4[r]; continue; }
        r -= SEG_OUTX;
        // --- features[0:N] = q_x ---
        if (r < SEG_QX) { out4[OFF_FEAT / 4 + r] = q_x4[r]; continue; }
        r -= SEG_QX;
        // --- features[N:2N] = k_x ---
        if (r < SEG_QX) { out4[OFF_FEAT / 4 + SEG_QX + r] = k_x4[r]; continue; }
        r -= SEG_QX;
        // --- queue read ONCE -> features[2N:] and new_queue (with k_x splice) ---
        if (r < SEG_QUEUE) {
            float4 qv = queue4[r];
            out4[OFF_FEAT / 4 + 2 * SEG_QX + r] = qv;
            int row = (int)(r >> 5);                 // D/4 = 32 float4 per row
            float4 nq = qv;
            if (row >= ptr && row < ptr + Nn)
                nq = k_x4[((long)(row - ptr) << 5) + (r & 31)];
            out4[OFF_NQ / 4 + r] = nq;
            continue;
        }
        r -= SEG_QUEUE;
        // --- targets = concat(Y, Y, queue_Y) as float (boundaries are /4-aligned) ---
        if (r < SEG_TGT) {
            int4 t;
            if (r < Nn / 4)            t = Y4[r];
            else if (r < 2 * Nn / 4)   t = Y4[r - Nn / 4];
            else                       t = qY4[r - 2 * Nn / 4];
            out4[OFF_TGT / 4 + r] =
                make_float4((float)t.x, (float)t.y, (float)t.z, (float)t.w);
            continue;
        }
        r -= SEG_TGT;
        // --- new_queue_Y: queue_Y with [ptr,ptr+N) = Y, as float ---
        if (r < SEG_QY) {
            int4 t = qY4[r];
            float4 o = make_float4((float)t.x, (float)t.y, (float)t.z, (float)t.w);
            long e0 = r << 2;
            if (e0 + 3 >= ptr && e0 < (long)ptr + Nn) {
                float* op = &o.x;
                #pragma unroll
                for (int c2 = 0; c2 < 4; ++c2) {
                    long e = e0 + c2;
                    if (e >= ptr && e < (long)ptr + Nn) op[c2] = (float)Y[e - ptr];
                }
            }
            out4[OFF_NQY / 4 + r] = o;
            continue;
        }
        r -= SEG_QY;
        // --- new_isID: isID with [ptr,ptr+N) = 1.0 ---
        if (r < SEG_QY) {
            float4 o = isID4[r];
            long e0 = r << 2;
            if (e0 + 3 >= ptr && e0 < (long)ptr + Nn) {
                float* op = &o.x;
                #pragma unroll
                for (int c2 = 0; c2 < 4; ++c2) {
                    long e = e0 + c2;
                    if (e >= ptr && e < (long)ptr + Nn) op[c2] = 1.0f;
                }
            }
            out4[OFF_ISID / 4 + r] = o;
            continue;
        }
        // --- single trailing item: new_ptr = (ptr + N) % Q ---
        out[OFF_PTR] = (float)((ptr_raw + Nn) % Qq);
    }
}

// One block per class c (1000 blocks x 128 threads). Thread d owns element d of
// the prototype row. Sequential scan over the N samples reproduces the exact
// per-sample EMA order; then L2-normalize via 2-wave reduction.
__global__ __launch_bounds__(128) void proto_kernel(
    const float* __restrict__ q_x, const float* __restrict__ protos,
    const int* __restrict__ Y, float* __restrict__ out_protos)
{
    const int c = blockIdx.x;
    const int d = threadIdx.x;
    float p = protos[(long)c * Dd + d];
    const float m = PROTO_M, om = 1.0f - PROTO_M;
    for (int i = 0; i < Nn; ++i) {
        int y = Y[i];                      // scalar (wave-uniform), L2-cached
        if (y == c) p = m * p + om * q_x[(long)i * Dd + d];
    }
    // sum of squares across 128 threads (2 waves of 64)
    float s = p * p;
    #pragma unroll
    for (int off = 32; off >= 1; off >>= 1) s += __shfl_xor(s, off);
    __shared__ float ws[2];
    if ((threadIdx.x & 63) == 0) ws[threadIdx.x >> 6] = s;
    __syncthreads();
    float norm = sqrtf(ws[0] + ws[1]);
    norm = fmaxf(norm, 1e-12f);
    out_protos[(long)c * Dd + d] = p / norm;
}

extern "C" void kernel_launch(void* const* d_in, const int* in_sizes, int n_in,
                              void* d_out, int out_size, void* d_ws, size_t ws_size,
                              hipStream_t stream)
{
    const float* q_x      = (const float*)d_in[0];
    const float* k_x      = (const float*)d_in[1];
    const float* output_x = (const float*)d_in[2];
    const float* queue    = (const float*)d_in[3];
    const float* protos   = (const float*)d_in[4];
    const float* isID     = (const float*)d_in[5];
    const int*   Y        = (const int*)d_in[6];
    const int*   queue_Y  = (const int*)d_in[7];
    const int*   ptr_p    = (const int*)d_in[8];
    float* out = (float*)d_out;

    hipLaunchKernelGGL(fuse_kernel, dim3(4096), dim3(256), 0, stream,
                       (const float4*)q_x, (const float4*)k_x,
                       (const float4*)output_x, (const float4*)queue,
                       (const float4*)isID, Y, queue_Y, ptr_p, out);

    hipLaunchKernelGGL(proto_kernel, dim3(Cc), dim3(Dd), 0, stream,
                       q_x, protos, Y, out + OFF_PROT);
}

// Round 3
// 81.438 us; speedup vs baseline: 1.2526x; 1.2526x over previous
//
#include <hip/hip_runtime.h>
#include <math.h>

// Problem constants (from reference): N=256, D=128, C=1000, Q=262144
constexpr int  Nn = 256;
constexpr int  Dd = 128;
constexpr int  Cc = 1000;
constexpr int  Qq = 262144;
constexpr float PROTO_M = 0.99f;

// clang-native vector types (usable with __builtin_nontemporal_*)
typedef float vf4 __attribute__((ext_vector_type(4)));
typedef int   vi4 __attribute__((ext_vector_type(4)));

// ---- float4-unit segment sizes for the big fused copy ----
constexpr long SEG_OUTX  = (long)Nn * Cc / 4;        // 64000   output_x copy
constexpr long SEG_QX    = (long)Nn * Dd / 4;        // 8192    q_x -> features
constexpr long SEG_QUEUE = (long)Qq * Dd / 4;        // 8388608 queue -> features + new_queue
constexpr long SEG_TGT   = (long)(2 * Nn + Qq) / 4;  // 65664   targets
constexpr long SEG_QY    = (long)Qq / 4;             // 65536   new_queue_Y / new_isID

// ---- output offsets in float units (tuple members flattened in order) ----
constexpr long OFF_OUTX = 0;
constexpr long OFF_FEAT = (long)Nn * Cc;                       // 256000
constexpr long OFF_TGT  = OFF_FEAT + (long)(2 * Nn + Qq) * Dd; // 33875968
constexpr long OFF_PROT = OFF_TGT + (2 * Nn + Qq);             // 34138624
constexpr long OFF_NQ   = OFF_PROT + (long)Cc * Dd;            // 34266624
constexpr long OFF_NQY  = OFF_NQ + (long)Qq * Dd;              // 67821056
constexpr long OFF_ISID = OFF_NQY + Qq;                        // 68083200
constexpr long OFF_PTR  = OFF_ISID + Qq;                       // 68345344

constexpr int PROTO_BLOCKS = Cc / 2;   // 500 blocks, 2 classes per 256-thread block
constexpr int COPY_BLOCKS  = 4096;

__global__ __launch_bounds__(256) void mega_kernel(
    const vf4* __restrict__ q_x4, const vf4* __restrict__ k_x4,
    const vf4* __restrict__ output_x4, const vf4* __restrict__ queue4,
    const float* __restrict__ protos, const vf4* __restrict__ isID4,
    const int* __restrict__ Y, const int* __restrict__ queue_Y,
    const int* __restrict__ ptr_p, float* __restrict__ out)
{
    // ---------------- prototype EMA + renormalize (blocks 0..499) -------------
    // Latency-bound; hides under the BW-bound copy done by the other blocks.
    if (blockIdx.x < PROTO_BLOCKS) {
        const float* q_x = (const float*)q_x4;
        const int grp = threadIdx.x >> 7;            // 0 or 1: which class
        const int c   = blockIdx.x * 2 + grp;
        const int d   = threadIdx.x & 127;
        float p = protos[(long)c * Dd + d];
        const float m = PROTO_M, om = 1.0f - PROTO_M;
        for (int i = 0; i < Nn; ++i) {
            int y = Y[i];                            // wave-uniform, L2-hot
            if (y == c) p = m * p + om * q_x[(long)i * Dd + d];
        }
        // sum of squares across the 128-thread group (2 waves)
        float s = p * p;
        #pragma unroll
        for (int off = 32; off >= 1; off >>= 1) s += __shfl_xor(s, off);
        __shared__ float ws[4];
        if ((threadIdx.x & 63) == 0) ws[threadIdx.x >> 6] = s;
        __syncthreads();
        float norm = fmaxf(sqrtf(ws[2 * grp] + ws[2 * grp + 1]), 1e-12f);
        out[OFF_PROT + (long)c * Dd + d] = p / norm;
        return;
    }

    // ---------------- fused streaming copy (remaining blocks) -----------------
    const long total = SEG_OUTX + 2 * SEG_QX + SEG_QUEUE + SEG_TGT + 2 * SEG_QY + 1;
    vf4* out4 = (vf4*)out;
    const vi4* Y4  = (const vi4*)Y;
    const vi4* qY4 = (const vi4*)queue_Y;

    const int ptr_raw = *ptr_p;
    const int ptr = min(max(ptr_raw, 0), Qq - Nn);   // dynamic_update_slice clamp

    const long stride = (long)COPY_BLOCKS * blockDim.x;
    for (long v = (long)(blockIdx.x - PROTO_BLOCKS) * blockDim.x + threadIdx.x;
         v < total; v += stride) {
        long r = v;
        // --- output_x passthrough ---
        if (r < SEG_OUTX) {
            vf4 t = __builtin_nontemporal_load(output_x4 + r);
            __builtin_nontemporal_store(t, out4 + OFF_OUTX / 4 + r);
            continue;
        }
        r -= SEG_OUTX;
        // --- features[0:N] = q_x ---
        if (r < SEG_QX) {
            vf4 t = q_x4[r];
            __builtin_nontemporal_store(t, out4 + OFF_FEAT / 4 + r);
            continue;
        }
        r -= SEG_QX;
        // --- features[N:2N] = k_x ---
        if (r < SEG_QX) {
            vf4 t = k_x4[r];
            __builtin_nontemporal_store(t, out4 + OFF_FEAT / 4 + SEG_QX + r);
            continue;
        }
        r -= SEG_QX;
        // --- queue read ONCE -> features[2N:] and new_queue (with k_x splice) ---
        if (r < SEG_QUEUE) {
            vf4 qv = __builtin_nontemporal_load(queue4 + r);
            __builtin_nontemporal_store(qv, out4 + OFF_FEAT / 4 + 2 * SEG_QX + r);
            int row = (int)(r >> 5);                 // D/4 = 32 float4 per row
            vf4 nq = qv;
            if (row >= ptr && row < ptr + Nn)
                nq = k_x4[((long)(row - ptr) << 5) + (r & 31)];
            __builtin_nontemporal_store(nq, out4 + OFF_NQ / 4 + r);
            continue;
        }
        r -= SEG_QUEUE;
        // --- targets = concat(Y, Y, queue_Y) as float (boundaries /4-aligned) ---
        if (r < SEG_TGT) {
            vi4 t;
            if (r < Nn / 4)            t = Y4[r];
            else if (r < 2 * Nn / 4)   t = Y4[r - Nn / 4];
            else                       t = qY4[r - 2 * Nn / 4];
            vf4 o = { (float)t.x, (float)t.y, (float)t.z, (float)t.w };
            __builtin_nontemporal_store(o, out4 + OFF_TGT / 4 + r);
            continue;
        }
        r -= SEG_TGT;
        // --- new_queue_Y: queue_Y with [ptr,ptr+N) = Y, as float ---
        if (r < SEG_QY) {
            vi4 t = qY4[r];
            vf4 o = { (float)t.x, (float)t.y, (float)t.z, (float)t.w };
            long e0 = r << 2;
            if (e0 + 3 >= ptr && e0 < (long)ptr + Nn) {
                #pragma unroll
                for (int c2 = 0; c2 < 4; ++c2) {
                    long e = e0 + c2;
                    if (e >= ptr && e < (long)ptr + Nn) o[c2] = (float)Y[e - ptr];
                }
            }
            __builtin_nontemporal_store(o, out4 + OFF_NQY / 4 + r);
            continue;
        }
        r -= SEG_QY;
        // --- new_isID: isID with [ptr,ptr+N) = 1.0 ---
        if (r < SEG_QY) {
            vf4 o = __builtin_nontemporal_load(isID4 + r);
            long e0 = r << 2;
            if (e0 + 3 >= ptr && e0 < (long)ptr + Nn) {
                #pragma unroll
                for (int c2 = 0; c2 < 4; ++c2) {
                    long e = e0 + c2;
                    if (e >= ptr && e < (long)ptr + Nn) o[c2] = 1.0f;
                }
            }
            __builtin_nontemporal_store(o, out4 + OFF_ISID / 4 + r);
            continue;
        }
        // --- single trailing item: new_ptr = (ptr + N) % Q ---
        out[OFF_PTR] = (float)((ptr_raw + Nn) % Qq);
    }
}

extern "C" void kernel_launch(void* const* d_in, const int* in_sizes, int n_in,
                              void* d_out, int out_size, void* d_ws, size_t ws_size,
                              hipStream_t stream)
{
    const float* q_x      = (const float*)d_in[0];
    const float* k_x      = (const float*)d_in[1];
    const float* output_x = (const float*)d_in[2];
    const float* queue    = (const float*)d_in[3];
    const float* protos   = (const float*)d_in[4];
    const float* isID     = (const float*)d_in[5];
    const int*   Y        = (const int*)d_in[6];
    const int*   queue_Y  = (const int*)d_in[7];
    const int*   ptr_p    = (const int*)d_in[8];
    float* out = (float*)d_out;

    hipLaunchKernelGGL(mega_kernel, dim3(PROTO_BLOCKS + COPY_BLOCKS), dim3(256), 0, stream,
                       (const vf4*)q_x, (const vf4*)k_x,
                       (const vf4*)output_x, (const vf4*)queue,
                       protos, (const vf4*)isID, Y, queue_Y, ptr_p, out);
}